// Round 2
// baseline (385.186 us; speedup 1.0000x reference)
//
#include <hip/hip_runtime.h>
#include <stdint.h>

#define B_ROWS 8192
#define DG 512
#define D2 768
#define D3 1024
#define DCAT 2304
#define DF 256
#define RANK 16
#define AH 512

// bf16 weight buffer element offsets
#define OFF_WG 0
#define OFF_W2 131072
#define OFF_W3 327680
#define OFF_U  589824
#define OFF_V  1638400
#define OFF_S  2686976
#define OFF_WA1 3735552
#define WTOT   4915200

// workspace byte offsets (total footprint 94,240,768 B)
#define WS_WBUF 0u
#define WS_GBUF 9830400u
#define WS_A1   22413312u
#define WS_BETA 30801920u
#define WS_HCAT 31326208u
#define WS_PROJ 69074944u
#define WS_ZR   31326208u   /* overlays hcat+proj, both dead before rank GEMMs */
#define WS_REQUIRED 94240768u

#define CHUNK 2048          /* rows per rank-GEMM/reduce chunk */

typedef __attribute__((ext_vector_type(8))) short short8;
typedef __attribute__((ext_vector_type(4))) float f32x4;

__device__ inline unsigned short f2bf(float f) {
  union { float f; unsigned int u; } v; v.f = f;
  unsigned int u = v.u + 0x7fffu + ((v.u >> 16) & 1u);
  return (unsigned short)(u >> 16);
}
__device__ inline float bf2f(unsigned short h) {
  union { float f; unsigned int u; } v; v.u = ((unsigned int)h) << 16;
  return v.f;
}

typedef const unsigned int __attribute__((address_space(1)))* as1_u32p;
typedef unsigned int __attribute__((address_space(3)))* as3_u32p;

__device__ inline void g2l16(const unsigned short* g, unsigned short* l) {
  __builtin_amdgcn_global_load_lds((as1_u32p)g, (as3_u32p)l, 16, 0, 0);
}

// ---------------- conversion kernels ----------------

__global__ __launch_bounds__(256) void cvt_hcat_k(const float* __restrict__ hg,
                                                  const float* __restrict__ h2,
                                                  const float* __restrict__ h3,
                                                  unsigned short* __restrict__ hcat) {
  const int idx = blockIdx.x * 256 + threadIdx.x;   // one float4 per thread
  const int e = idx * 4;
  const int row = e / DCAT;
  const int col = e - row * DCAT;
  const float* src;
  if (col < DG) src = hg + (size_t)row * DG + col;
  else if (col < DG + D2) src = h2 + (size_t)row * D2 + (col - DG);
  else src = h3 + (size_t)row * D3 + (col - DG - D2);
  float4 v = *(const float4*)src;
  ushort4 o;
  o.x = f2bf(v.x); o.y = f2bf(v.y); o.z = f2bf(v.z); o.w = f2bf(v.w);
  *(ushort4*)(hcat + e) = o;
}

__global__ __launch_bounds__(256) void cvt_weights_k(const float* __restrict__ Wg,
                                                     const float* __restrict__ W2,
                                                     const float* __restrict__ W3,
                                                     const float* __restrict__ U,
                                                     const float* __restrict__ V,
                                                     const float* __restrict__ S,
                                                     const float* __restrict__ Wa1,
                                                     unsigned short* __restrict__ wbuf) {
  const int idx = blockIdx.x * 256 + threadIdx.x;
  const int e = idx * 4;
  const float* src;
  if (e < OFF_W2)       src = Wg  + e;
  else if (e < OFF_W3)  src = W2  + (e - OFF_W2);
  else if (e < OFF_U)   src = W3  + (e - OFF_W3);
  else if (e < OFF_V)   src = U   + (e - OFF_U);
  else if (e < OFF_S)   src = V   + (e - OFF_V);
  else if (e < OFF_WA1) src = S   + (e - OFF_S);
  else                  src = Wa1 + (e - OFF_WA1);
  float4 v = *(const float4*)src;
  ushort4 o;
  o.x = f2bf(v.x); o.y = f2bf(v.y); o.z = f2bf(v.z); o.w = f2bf(v.w);
  *(ushort4*)(wbuf + e) = o;
}

// ---------------- shared GEMM mainloop (m97 recipe) ----------------
// 128x128 block tile, BK=64, 256 threads = 4 waves in 2x2, wave tile 64x64,
// 4x4 fragments of v_mfma_f32_16x16x32_bf16, global_load_lds width-16 staging.

__device__ __forceinline__ void gemm_mainloop(const unsigned short* Ag, int lda,
                                              const unsigned short* Bg, int ldb,
                                              int K,
                                              unsigned short* lA, unsigned short* lB,
                                              f32x4 acc[4][4]) {
  const int tid = threadIdx.x;
  const int lane = tid & 63;
  const int wr = tid >> 7;
  const int wc = (tid >> 6) & 1;
#pragma unroll
  for (int i = 0; i < 4; ++i)
#pragma unroll
    for (int j = 0; j < 4; ++j)
      acc[i][j] = (f32x4){0.f, 0.f, 0.f, 0.f};

  const int row_s = tid >> 3;        // staging: 8 x 16B chunks per 64-elem row
  const int kc_s = (tid & 7) << 3;
  const int mbase = wr * 64 + (lane & 15);
  const int nbase = wc * 64 + (lane & 15);
  const int kfrag = (lane >> 4) * 8;

  const int nsteps = K >> 6;
  for (int ks = 0; ks < nsteps; ++ks) {
    const int k0 = ks << 6;
    __syncthreads();
#pragma unroll
    for (int p = 0; p < 4; ++p) {
      const int row = p * 32 + row_s;
      const int lofs = (p * 256 + tid) * 8;
      g2l16(Ag + (size_t)row * lda + k0 + kc_s, lA + lofs);
      g2l16(Bg + (size_t)row * ldb + k0 + kc_s, lB + lofs);
    }
    __syncthreads();
#pragma unroll
    for (int kk = 0; kk < 2; ++kk) {
      short8 af[4], bfr[4];
#pragma unroll
      for (int t = 0; t < 4; ++t) {
        af[t]  = *(const short8*)(lA + (mbase + t * 16) * 64 + kk * 32 + kfrag);
        bfr[t] = *(const short8*)(lB + (nbase + t * 16) * 64 + kk * 32 + kfrag);
      }
#pragma unroll
      for (int ti = 0; ti < 4; ++ti)
#pragma unroll
        for (int tj = 0; tj < 4; ++tj)
          acc[ti][tj] = __builtin_amdgcn_mfma_f32_16x16x32_bf16(af[ti], bfr[tj], acc[ti][tj], 0, 0, 0);
    }
  }
}

// ---------------- GEMM kernels ----------------

// proj[z] = hcat_seg @ Wm^T  (fp32 out; bias/LN applied later)
__global__ __launch_bounds__(256) void gemm_proj_k(const unsigned short* __restrict__ hcat,
                                                   const unsigned short* __restrict__ wbuf,
                                                   float* __restrict__ proj) {
  __shared__ __align__(16) unsigned short lA[128 * 64];
  __shared__ __align__(16) unsigned short lB[128 * 64];
  const int z = blockIdx.z;
  const int Kz   = (z == 0) ? DG : (z == 1 ? D2 : D3);
  const int aoff = (z == 0) ? 0  : (z == 1 ? DG : DG + D2);
  const int woff = (z == 0) ? OFF_WG : (z == 1 ? OFF_W2 : OFF_W3);
  const int m0 = blockIdx.x * 128, n0 = blockIdx.y * 128;
  f32x4 acc[4][4];
  gemm_mainloop(hcat + (size_t)m0 * DCAT + aoff, DCAT,
                wbuf + woff + (size_t)n0 * Kz, Kz, Kz, lA, lB, acc);
  float* out = proj + (size_t)z * B_ROWS * DF;
  const int lane = threadIdx.x & 63;
  const int wr = threadIdx.x >> 7, wc = (threadIdx.x >> 6) & 1;
  const int r0 = m0 + wr * 64 + ((lane >> 4) << 2);
  const int c0 = n0 + wc * 64 + (lane & 15);
#pragma unroll
  for (int ti = 0; ti < 4; ++ti)
#pragma unroll
    for (int tj = 0; tj < 4; ++tj)
#pragma unroll
      for (int i = 0; i < 4; ++i)
        out[(size_t)(r0 + ti * 16 + i) * DF + (c0 + tj * 16)] = acc[ti][tj][i];
}

// a1 = relu(hcat @ Wa1^T + ba1), bf16 out
__global__ __launch_bounds__(256) void gemm_a1_k(const unsigned short* __restrict__ hcat,
                                                 const unsigned short* __restrict__ wbuf,
                                                 const float* __restrict__ ba1,
                                                 unsigned short* __restrict__ a1) {
  __shared__ __align__(16) unsigned short lA[128 * 64];
  __shared__ __align__(16) unsigned short lB[128 * 64];
  const int m0 = blockIdx.x * 128, n0 = blockIdx.y * 128;
  f32x4 acc[4][4];
  gemm_mainloop(hcat + (size_t)m0 * DCAT, DCAT,
                wbuf + OFF_WA1 + (size_t)n0 * DCAT, DCAT, DCAT, lA, lB, acc);
  const int lane = threadIdx.x & 63;
  const int wr = threadIdx.x >> 7, wc = (threadIdx.x >> 6) & 1;
  const int r0 = m0 + wr * 64 + ((lane >> 4) << 2);
  const int c0 = n0 + wc * 64 + (lane & 15);
#pragma unroll
  for (int tj = 0; tj < 4; ++tj) {
    const float bcol = ba1[c0 + tj * 16];
#pragma unroll
    for (int ti = 0; ti < 4; ++ti)
#pragma unroll
      for (int i = 0; i < 4; ++i) {
        const float v = fmaxf(acc[ti][tj][i] + bcol, 0.f);
        a1[(size_t)(r0 + ti * 16 + i) * AH + (c0 + tj * 16)] = f2bf(v);
      }
  }
}

// z_r[z] = gbuf[z][rowbase..rowbase+CHUNK] @ {U,V,S}^T, bf16 out (CHUNK x 4096 each)
__global__ __launch_bounds__(256) void gemm_rank_k(const unsigned short* __restrict__ gbuf,
                                                   const unsigned short* __restrict__ wbuf,
                                                   unsigned short* __restrict__ zr,
                                                   int rowbase) {
  __shared__ __align__(16) unsigned short lA[128 * 64];
  __shared__ __align__(16) unsigned short lB[128 * 64];
  const int z = blockIdx.z;
  const int m0 = blockIdx.x * 128, n0 = blockIdx.y * 128;
  f32x4 acc[4][4];
  gemm_mainloop(gbuf + (size_t)z * B_ROWS * DF + (size_t)(rowbase + m0) * DF, DF,
                wbuf + OFF_U + (size_t)z * 1048576 + (size_t)n0 * DF, DF, DF, lA, lB, acc);
  unsigned short* out = zr + (size_t)z * CHUNK * 4096;
  const int lane = threadIdx.x & 63;
  const int wr = threadIdx.x >> 7, wc = (threadIdx.x >> 6) & 1;
  const int r0 = m0 + wr * 64 + ((lane >> 4) << 2);
  const int c0 = n0 + wc * 64 + (lane & 15);
#pragma unroll
  for (int ti = 0; ti < 4; ++ti)
#pragma unroll
    for (int tj = 0; tj < 4; ++tj)
#pragma unroll
      for (int i = 0; i < 4; ++i)
        out[(size_t)(r0 + ti * 16 + i) * 4096 + (c0 + tj * 16)] = f2bf(acc[ti][tj][i]);
}

// ---------------- LN + ReLU (fp32 stats over 256 cols, one wave per row) ----------------

__global__ __launch_bounds__(256) void ln_relu_k(const float* __restrict__ proj,
                                                 const float* __restrict__ bg, const float* __restrict__ b2, const float* __restrict__ b3,
                                                 const float* __restrict__ wg, const float* __restrict__ wbg,
                                                 const float* __restrict__ w2, const float* __restrict__ wb2,
                                                 const float* __restrict__ w3, const float* __restrict__ wb3,
                                                 unsigned short* __restrict__ gout) {
  const int gid = blockIdx.x * 4 + (threadIdx.x >> 6);
  const int lane = threadIdx.x & 63;
  const int z = gid >> 13;
  const int row = gid & (B_ROWS - 1);
  const float* bias = z == 0 ? bg : (z == 1 ? b2 : b3);
  const float* lw = z == 0 ? wg : (z == 1 ? w2 : w3);
  const float* lb = z == 0 ? wbg : (z == 1 ? wb2 : wb3);
  const float* x = proj + (size_t)z * B_ROWS * DF + (size_t)row * DF + lane * 4;
  float4 v = *(const float4*)x;
  float4 bb = *(const float4*)(bias + lane * 4);
  v.x += bb.x; v.y += bb.y; v.z += bb.z; v.w += bb.w;
  float s = v.x + v.y + v.z + v.w;
  float q = v.x * v.x + v.y * v.y + v.z * v.z + v.w * v.w;
#pragma unroll
  for (int m = 1; m < 64; m <<= 1) { s += __shfl_xor(s, m, 64); q += __shfl_xor(q, m, 64); }
  const float mean = s * (1.f / DF);
  const float var = q * (1.f / DF) - mean * mean;
  const float rs = rsqrtf(var + 1e-5f);
  float4 w4 = *(const float4*)(lw + lane * 4);
  float4 b4 = *(const float4*)(lb + lane * 4);
  ushort4 o;
  o.x = f2bf(fmaxf((v.x - mean) * rs * w4.x + b4.x, 0.f));
  o.y = f2bf(fmaxf((v.y - mean) * rs * w4.y + b4.y, 0.f));
  o.z = f2bf(fmaxf((v.z - mean) * rs * w4.z + b4.z, 0.f));
  o.w = f2bf(fmaxf((v.w - mean) * rs * w4.w + b4.w, 0.f));
  *(ushort4*)(gout + (size_t)z * B_ROWS * DF + (size_t)row * DF + lane * 4) = o;
}

// ---------------- logits + softmax -> beta (fp32) ----------------

__global__ __launch_bounds__(256) void attn_beta_k(const unsigned short* __restrict__ a1,
                                                   const float* __restrict__ Wa2,
                                                   const float* __restrict__ ba2,
                                                   float* __restrict__ beta) {
  __shared__ float lw[RANK * AH];  // 32 KB
  for (int i = threadIdx.x; i < RANK * AH / 4; i += 256)
    *(float4*)(lw + i * 4) = *(const float4*)(Wa2 + i * 4);
  __syncthreads();
  const int row = blockIdx.x * 4 + (threadIdx.x >> 6);
  const int lane = threadIdx.x & 63;
  const uint4 pk = *(const uint4*)(a1 + (size_t)row * AH + lane * 8);
  const unsigned int pu[4] = {pk.x, pk.y, pk.z, pk.w};
  float av[8];
#pragma unroll
  for (int j = 0; j < 4; ++j) {
    av[2 * j] = bf2f((unsigned short)(pu[j] & 0xffffu));
    av[2 * j + 1] = bf2f((unsigned short)(pu[j] >> 16));
  }
  float lg[RANK];
#pragma unroll
  for (int r = 0; r < RANK; ++r) {
    const float* wrow = lw + r * AH + lane * 8;
    float4 wa = *(const float4*)wrow;
    float4 wb = *(const float4*)(wrow + 4);
    float p = av[0] * wa.x + av[1] * wa.y + av[2] * wa.z + av[3] * wa.w
            + av[4] * wb.x + av[5] * wb.y + av[6] * wb.z + av[7] * wb.w;
#pragma unroll
    for (int m = 1; m < 64; m <<= 1) p += __shfl_xor(p, m, 64);
    lg[r] = p + ba2[r];
  }
  float mx = lg[0];
#pragma unroll
  for (int r = 1; r < RANK; ++r) mx = fmaxf(mx, lg[r]);
  float den = 0.f;
#pragma unroll
  for (int r = 0; r < RANK; ++r) { lg[r] = __expf(lg[r] - mx); den += lg[r]; }
  const float inv = 1.f / den;
  if (lane < RANK) {
    float mine = 0.f;
#pragma unroll
    for (int r = 0; r < RANK; ++r) mine = (lane == r) ? lg[r] : mine;
    beta[(size_t)row * RANK + lane] = mine * inv;
  }
}

// ---------------- tri-linear product + beta-weighted rank reduce (per chunk) ----------------

__global__ __launch_bounds__(256) void zreduce_k(const unsigned short* __restrict__ zr,
                                                 const float* __restrict__ beta,
                                                 float* __restrict__ out,
                                                 int rowbase) {
  const int row_local = blockIdx.x;
  const int row = rowbase + row_local;
  const int d = threadIdx.x;
  __shared__ float lbeta[RANK];
  if (threadIdx.x < RANK) lbeta[threadIdx.x] = beta[(size_t)row * RANK + threadIdx.x];
  __syncthreads();
  const unsigned short* g = zr + (size_t)row_local * 4096;
  const unsigned short* v = g + (size_t)CHUNK * 4096;
  const unsigned short* s = v + (size_t)CHUNK * 4096;
  float acc = 0.f;
#pragma unroll
  for (int r = 0; r < RANK; ++r) {
    const int idx = r * 256 + d;
    acc += lbeta[r] * bf2f(g[idx]) * bf2f(v[idx]) * bf2f(s[idx]);
  }
  out[(size_t)row * DF + d] = acc;
}

// ---------------- launch ----------------

extern "C" void kernel_launch(void* const* d_in, const int* in_sizes, int n_in,
                              void* d_out, int out_size, void* d_ws, size_t ws_size,
                              hipStream_t stream) {
  if (ws_size < (size_t)WS_REQUIRED) return;  // diagnostic guard: clean fail if ws too small

  const float* h_g   = (const float*)d_in[0];
  const float* h_2d  = (const float*)d_in[1];
  const float* h_3d  = (const float*)d_in[2];
  const float* Wg    = (const float*)d_in[3];
  const float* bg    = (const float*)d_in[4];
  const float* W2    = (const float*)d_in[5];
  const float* b2    = (const float*)d_in[6];
  const float* W3    = (const float*)d_in[7];
  const float* b3    = (const float*)d_in[8];
  const float* ln_g_w = (const float*)d_in[9];
  const float* ln_g_b = (const float*)d_in[10];
  const float* ln_2_w = (const float*)d_in[11];
  const float* ln_2_b = (const float*)d_in[12];
  const float* ln_3_w = (const float*)d_in[13];
  const float* ln_3_b = (const float*)d_in[14];
  const float* U     = (const float*)d_in[15];
  const float* V     = (const float*)d_in[16];
  const float* S     = (const float*)d_in[17];
  const float* Wa1   = (const float*)d_in[18];
  const float* ba1   = (const float*)d_in[19];
  const float* Wa2   = (const float*)d_in[20];
  const float* ba2   = (const float*)d_in[21];

  char* ws = (char*)d_ws;
  unsigned short* wbuf = (unsigned short*)(ws + WS_WBUF);
  unsigned short* gbuf = (unsigned short*)(ws + WS_GBUF);
  unsigned short* a1   = (unsigned short*)(ws + WS_A1);
  float*          beta = (float*)(ws + WS_BETA);
  unsigned short* hcat = (unsigned short*)(ws + WS_HCAT);
  float*          proj = (float*)(ws + WS_PROJ);
  unsigned short* zr   = (unsigned short*)(ws + WS_ZR);   // overlays hcat+proj
  float* z = (float*)d_out;

  cvt_hcat_k<<<dim3(18432), dim3(256), 0, stream>>>(h_g, h_2d, h_3d, hcat);
  cvt_weights_k<<<dim3(4800), dim3(256), 0, stream>>>(Wg, W2, W3, U, V, S, Wa1, wbuf);
  gemm_proj_k<<<dim3(64, 2, 3), dim3(256), 0, stream>>>(hcat, wbuf, proj);
  ln_relu_k<<<dim3(6144), dim3(256), 0, stream>>>(proj, bg, b2, b3, ln_g_w, ln_g_b,
                                                  ln_2_w, ln_2_b, ln_3_w, ln_3_b, gbuf);
  gemm_a1_k<<<dim3(64, 4), dim3(256), 0, stream>>>(hcat, wbuf, ba1, a1);
  attn_beta_k<<<dim3(2048), dim3(256), 0, stream>>>(a1, Wa2, ba2, beta);
  // hcat and proj are dead from here on; zr overlays them.
  for (int c = 0; c < B_ROWS / CHUNK; ++c) {
    const int rowbase = c * CHUNK;
    gemm_rank_k<<<dim3(CHUNK / 128, 32, 3), dim3(256), 0, stream>>>(gbuf, wbuf, zr, rowbase);
    zreduce_k<<<dim3(CHUNK), dim3(256), 0, stream>>>(zr, beta, z, rowbase);
  }
}